// Round 6
// baseline (495.585 us; speedup 1.0000x reference)
//
#include <hip/hip_runtime.h>

// Problem constants
constexpr int NB = 8, NH = 8, NN = 1024, DK = 64, ED = 16;
constexpr long QSZ = (long)NB * NH * NN * DK;       // 4,194,304

typedef _Float16 h8 __attribute__((ext_vector_type(8)));
typedef _Float16 h4 __attribute__((ext_vector_type(4)));
typedef _Float16 h2 __attribute__((ext_vector_type(2)));
typedef float f4 __attribute__((ext_vector_type(4)));
typedef float fv16 __attribute__((ext_vector_type(16)));

// ws layout (bytes)
constexpr size_t OFF_QH = 0;                         // 8 MiB fp16 (pre-scaled by 0.125*log2e)
constexpr size_t OFF_KH = 8388608;                   // 8 MiB fp16
constexpr size_t OFF_VT = 16777216;                  // 8 MiB fp16 (transposed [bh][d][k])
constexpr size_t OFF_BIAS = 25165824;                // 32 MiB fp32 (bias*log2e, masked=-1e9)
constexpr size_t OFF_FLAG = 58720256;                // 4 B
constexpr size_t WS_NEED = OFF_FLAG + 4;

constexpr float LG2E = 1.4426950408889634f;          // log2(e)
constexpr float C2 = 2.8853900817779268f;            // 2*log2(e)
constexpr float QS = 0.125f * LG2E;                  // fold 1/sqrt(dk) and log2e into Q

static __device__ __forceinline__ float fexp2(float x) {
  float r; asm("v_exp_f32 %0, %1" : "=v"(r) : "v"(x)); return r;
}
static __device__ __forceinline__ float frcp(float x) {
  float r; asm("v_rcp_f32 %0, %1" : "=v"(r) : "v"(x)); return r;
}
static __device__ __forceinline__ h2 pkrtz(float a, float b) {
  return __builtin_bit_cast(h2, __builtin_amdgcn_cvt_pkrtz(a, b));
}

// ---------- prep: Q (x 0.125*log2e) and K -> fp16, same layout ----------
__global__ __launch_bounds__(256) void k_prep_qk(
    const float* __restrict__ Q, const float* __restrict__ K,
    _Float16* __restrict__ Qh, _Float16* __restrict__ Kh) {
  int i = blockIdx.x * 256 + threadIdx.x;
  const int n4 = (int)(QSZ / 4);
  if (i < n4) {
    float4 v = reinterpret_cast<const float4*>(Q)[i];
    h4 o; o[0] = (_Float16)(v.x * QS); o[1] = (_Float16)(v.y * QS);
          o[2] = (_Float16)(v.z * QS); o[3] = (_Float16)(v.w * QS);
    reinterpret_cast<h4*>(Qh)[i] = o;
  } else {
    int j = i - n4;
    float4 v = reinterpret_cast<const float4*>(K)[j];
    h4 o; o[0] = (_Float16)v.x; o[1] = (_Float16)v.y;
          o[2] = (_Float16)v.z; o[3] = (_Float16)v.w;
    reinterpret_cast<h4*>(Kh)[j] = o;
  }
}

// ---------- prep: V [bh][k][d] fp32 -> Vt [bh][d][k] fp16 ----------
__global__ __launch_bounds__(256) void k_prep_vt(
    const float* __restrict__ V, _Float16* __restrict__ Vt) {
  int wid = (blockIdx.x * 256 + threadIdx.x) >> 6;   // 4096 waves
  int lane = threadIdx.x & 63;
  int bh = wid >> 6;
  int k0 = (wid & 63) << 4;
  const float* Vb = V + (long)bh * NN * DK;
  _Float16* Vo = Vt + (long)bh * DK * NN + (long)lane * NN + k0;
  h8 p0, p1;
#pragma unroll
  for (int i = 0; i < 16; ++i) {
    float v = Vb[(long)(k0 + i) * DK + lane];
    if (i < 8) p0[i] = (_Float16)v; else p1[i - 8] = (_Float16)v;
  }
  *reinterpret_cast<h8*>(Vo) = p0;
  *reinterpret_cast<h8*>(Vo + 8) = p1;
}

// ---------- detect mask element width (bool bytes vs int32) ----------
__global__ void k_detect(const unsigned char* __restrict__ m, int* __restrict__ flag) {
  int t = threadIdx.x;
  int any = 0;
  for (int i = t; i < 4096; i += 256)
    if ((i & 3) && m[i]) any = 1;          // int32 0/1 never has nonzero at %4!=0
  unsigned long long b = __ballot(any);
  if ((t & 63) == 0 && b) atomicOr(flag, 1);
}

// ---------- edge-bias MLP + mask fold: biasM[b][q][k] = bias*log2e (or -1e9) ----------
// (unchanged from R5 — 32x32x16 MFMA, K=ED=16, full-lane, coalesced stores)
__global__ __launch_bounds__(256) void k_bias(
    const float* __restrict__ edge, const void* __restrict__ maskp,
    const float* __restrict__ W1, const float* __restrict__ b1,
    const float* __restrict__ W2, const float* __restrict__ b2,
    const int* __restrict__ flag, float* __restrict__ biasM) {
  int bq = blockIdx.x;
  int w = threadIdx.x >> 6, l = threadIdx.x & 63;
  int h = l >> 5, c31 = l & 31;
  bool isbool = (*flag != 0);
  h8 aw0, aw1;
#pragma unroll
  for (int j = 0; j < 8; ++j) {
    aw0[j] = (_Float16)(W1[(8 * h + j) * 64 + 0  + c31] * C2);
    aw1[j] = (_Float16)(W1[(8 * h + j) * 64 + 32 + c31] * C2);
  }
  fv16 cb0, cb1;
  float w20[16], w21[16];
  float sw = 0.f;
#pragma unroll
  for (int r = 0; r < 16; ++r) {
    int dr = (r & 3) + 8 * (r >> 2) + 4 * h;
    cb0[r] = b1[dr] * C2;      w20[r] = W2[dr];
    cb1[r] = b1[32 + dr] * C2; w21[r] = W2[32 + dr];
    sw += w20[r] + w21[r];
  }
  sw += __shfl_xor(sw, 32, 64);
  float base = (sw + b2[0]) * LG2E;

  const float* erow = edge + (long)bq * NN * ED;
  const float4* erow4 = reinterpret_cast<const float4*>(erow);
  float* orow = biasM + (long)bq * NN;
  const int* mrowi = (const int*)maskp + (long)bq * NN;
  const unsigned char* mrowb = (const unsigned char*)maskp + (long)bq * NN;

  int kbase = w * 256;
  float4 e0a = erow4[(kbase + c31) * 4 + 2 * h];
  float4 e0b = erow4[(kbase + c31) * 4 + 2 * h + 1];
  float4 e1a = erow4[(kbase + 32 + c31) * 4 + 2 * h];
  float4 e1b = erow4[(kbase + 32 + c31) * 4 + 2 * h + 1];
#pragma unroll
  for (int p = 0; p < 4; ++p) {
    float4 n0a, n0b, n1a, n1b;
    if (p < 3) {
      int nb = kbase + 64;
      n0a = erow4[(nb + c31) * 4 + 2 * h];
      n0b = erow4[(nb + c31) * 4 + 2 * h + 1];
      n1a = erow4[(nb + 32 + c31) * 4 + 2 * h];
      n1b = erow4[(nb + 32 + c31) * 4 + 2 * h + 1];
    }
    union { h8 v; h2 q[4]; } u0, u1;
    u0.q[0] = pkrtz(e0a.x, e0a.y); u0.q[1] = pkrtz(e0a.z, e0a.w);
    u0.q[2] = pkrtz(e0b.x, e0b.y); u0.q[3] = pkrtz(e0b.z, e0b.w);
    u1.q[0] = pkrtz(e1a.x, e1a.y); u1.q[1] = pkrtz(e1a.z, e1a.w);
    u1.q[2] = pkrtz(e1b.x, e1b.y); u1.q[3] = pkrtz(e1b.z, e1b.w);
    fv16 hA0 = __builtin_amdgcn_mfma_f32_32x32x16_f16(aw0, u0.v, cb0, 0, 0, 0);
    fv16 hB0 = __builtin_amdgcn_mfma_f32_32x32x16_f16(aw1, u0.v, cb1, 0, 0, 0);
    fv16 hA1 = __builtin_amdgcn_mfma_f32_32x32x16_f16(aw0, u1.v, cb0, 0, 0, 0);
    fv16 hB1 = __builtin_amdgcn_mfma_f32_32x32x16_f16(aw1, u1.v, cb1, 0, 0, 0);
    float a00 = 0.f, a01 = 0.f, a02 = 0.f, a03 = 0.f;
    float a10 = 0.f, a11 = 0.f, a12 = 0.f, a13 = 0.f;
#pragma unroll
    for (int r = 0; r < 16; r += 4) {
      a00 = fmaf(w20[r + 0], frcp(fexp2(hA0[r + 0]) + 1.f), a00);
      a01 = fmaf(w20[r + 1], frcp(fexp2(hA0[r + 1]) + 1.f), a01);
      a02 = fmaf(w20[r + 2], frcp(fexp2(hA0[r + 2]) + 1.f), a02);
      a03 = fmaf(w20[r + 3], frcp(fexp2(hA0[r + 3]) + 1.f), a03);
      a00 = fmaf(w21[r + 0], frcp(fexp2(hB0[r + 0]) + 1.f), a00);
      a01 = fmaf(w21[r + 1], frcp(fexp2(hB0[r + 1]) + 1.f), a01);
      a02 = fmaf(w21[r + 2], frcp(fexp2(hB0[r + 2]) + 1.f), a02);
      a03 = fmaf(w21[r + 3], frcp(fexp2(hB0[r + 3]) + 1.f), a03);
      a10 = fmaf(w20[r + 0], frcp(fexp2(hA1[r + 0]) + 1.f), a10);
      a11 = fmaf(w20[r + 1], frcp(fexp2(hA1[r + 1]) + 1.f), a11);
      a12 = fmaf(w20[r + 2], frcp(fexp2(hA1[r + 2]) + 1.f), a12);
      a13 = fmaf(w20[r + 3], frcp(fexp2(hA1[r + 3]) + 1.f), a13);
      a10 = fmaf(w21[r + 0], frcp(fexp2(hB1[r + 0]) + 1.f), a10);
      a11 = fmaf(w21[r + 1], frcp(fexp2(hB1[r + 1]) + 1.f), a11);
      a12 = fmaf(w21[r + 2], frcp(fexp2(hB1[r + 2]) + 1.f), a12);
      a13 = fmaf(w21[r + 3], frcp(fexp2(hB1[r + 3]) + 1.f), a13);
    }
    float p0 = (a00 + a01) + (a02 + a03);
    float p1 = (a10 + a11) + (a12 + a13);
    p0 += __shfl_xor(p0, 32, 64);
    p1 += __shfl_xor(p1, 32, 64);
    float part = h ? p1 : p0;
    int idx = kbase + 32 * h + c31;
    int m = isbool ? (int)mrowb[idx] : mrowi[idx];
    orow[idx] = m ? -1e9f : fmaf(-C2, part, base);
    e0a = n0a; e0b = n0b; e1a = n1a; e1b = n1b;
    kbase += 64;
  }
}

// ---------- fused attention (swapped-QK, LDS-free) ----------
// acc = mfma(K_frag as A, Q_frag as B, bias as C) -> D[kv][q]:
//   lane (g,s): acc[j] = S'[kv0+4g+j][q0+s]  (row=kv=4g+j, col=q=s)
// Bias enters as C-operand (float4 load). P = exp2(acc)*iv is exactly the
// B-fragment of v_mfma_f32_16x16x16_f16 (k=4g+j, col=s) -> PV with zero LDS.
__global__ __launch_bounds__(256) void k_attn(
    const _Float16* __restrict__ Qh, const _Float16* __restrict__ Kh,
    const _Float16* __restrict__ Vt, const float* __restrict__ biasM,
    float* __restrict__ ctx, float* __restrict__ attn) {
  int bid = blockIdx.x;
  int bh = bid >> 4, qb = bid & 15;
  int b = bh >> 3;
  int w = threadIdx.x >> 6, l = threadIdx.x & 63;
  int g = l >> 4, s = l & 15;
  int q0 = qb * 64 + w * 16;
  const _Float16* Qw = Qh + ((long)bh * NN + q0) * DK;
  const _Float16* Kb = Kh + (long)bh * NN * DK;
  const _Float16* Vb = Vt + (long)bh * DK * NN;
  const float* biasq = biasM + (long)b * NN * NN + (long)(q0 + s) * NN;
  h8 aQ0 = *reinterpret_cast<const h8*>(Qw + s * DK + 8 * g);
  h8 aQ1 = *reinterpret_cast<const h8*>(Qw + s * DK + 32 + 8 * g);

  // pass 1: row sums of exp2(S')  (lane accumulates its 4 kv per chunk)
  float ls = 0.f;
  for (int c0 = 0; c0 < NN; c0 += 32) {
#pragma unroll
    for (int ct = 0; ct < 2; ++ct) {
      int kv = c0 + ct * 16;
      const _Float16* kp = Kb + (long)(kv + s) * DK + 8 * g;
      h8 ak0 = *reinterpret_cast<const h8*>(kp);
      h8 ak1 = *reinterpret_cast<const h8*>(kp + 32);
      f4 cb = *reinterpret_cast<const f4*>(biasq + kv + 4 * g);
      f4 acc = __builtin_amdgcn_mfma_f32_16x16x32_f16(ak0, aQ0, cb, 0, 0, 0);
      acc = __builtin_amdgcn_mfma_f32_16x16x32_f16(ak1, aQ1, acc, 0, 0, 0);
      ls += fexp2(acc[0]); ls += fexp2(acc[1]);
      ls += fexp2(acc[2]); ls += fexp2(acc[3]);
    }
  }
  ls += __shfl_xor(ls, 16, 64);
  ls += __shfl_xor(ls, 32, 64);
  float iv = frcp(ls);

  // pass 2: recompute S', write attn (float4), PV straight from registers
  f4 ca0 = {0.f,0.f,0.f,0.f}, ca1 = {0.f,0.f,0.f,0.f};
  f4 ca2 = {0.f,0.f,0.f,0.f}, ca3 = {0.f,0.f,0.f,0.f};
  float* attnq = attn + ((long)bh * NN + q0 + s) * NN;
  for (int c0 = 0; c0 < NN; c0 += 32) {
#pragma unroll
    for (int ct = 0; ct < 2; ++ct) {
      int kv = c0 + ct * 16;
      const _Float16* kp = Kb + (long)(kv + s) * DK + 8 * g;
      h8 ak0 = *reinterpret_cast<const h8*>(kp);
      h8 ak1 = *reinterpret_cast<const h8*>(kp + 32);
      f4 cb = *reinterpret_cast<const f4*>(biasq + kv + 4 * g);
      f4 acc = __builtin_amdgcn_mfma_f32_16x16x32_f16(ak0, aQ0, cb, 0, 0, 0);
      acc = __builtin_amdgcn_mfma_f32_16x16x32_f16(ak1, aQ1, acc, 0, 0, 0);
      float p0 = fexp2(acc[0]) * iv;
      float p1 = fexp2(acc[1]) * iv;
      float p2 = fexp2(acc[2]) * iv;
      float p3 = fexp2(acc[3]) * iv;
      f4 po = {p0, p1, p2, p3};
      *reinterpret_cast<f4*>(attnq + kv + 4 * g) = po;   // one dwordx4 store
      union { h4 v; h2 q[2]; } pu;
      pu.q[0] = pkrtz(p0, p1); pu.q[1] = pkrtz(p2, p3);
      const _Float16* vp = Vb + (long)s * NN + kv + 4 * g;
      h4 va0 = *reinterpret_cast<const h4*>(vp);
      h4 va1 = *reinterpret_cast<const h4*>(vp + 16 * NN);
      h4 va2 = *reinterpret_cast<const h4*>(vp + 32 * NN);
      h4 va3 = *reinterpret_cast<const h4*>(vp + 48 * NN);
      ca0 = __builtin_amdgcn_mfma_f32_16x16x16f16(va0, pu.v, ca0, 0, 0, 0);
      ca1 = __builtin_amdgcn_mfma_f32_16x16x16f16(va1, pu.v, ca1, 0, 0, 0);
      ca2 = __builtin_amdgcn_mfma_f32_16x16x16f16(va2, pu.v, ca2, 0, 0, 0);
      ca3 = __builtin_amdgcn_mfma_f32_16x16x16f16(va3, pu.v, ca3, 0, 0, 0);
    }
  }
  // ctx[(q0+s)][d]: D[d_local=4g+j][q=s] per 16-d block t -> float4 stores
  float* cw = ctx + ((long)bh * NN + q0 + s) * DK;
  *reinterpret_cast<f4*>(cw + 0  + 4 * g) = ca0;
  *reinterpret_cast<f4*>(cw + 16 + 4 * g) = ca1;
  *reinterpret_cast<f4*>(cw + 32 + 4 * g) = ca2;
  *reinterpret_cast<f4*>(cw + 48 + 4 * g) = ca3;
}

extern "C" void kernel_launch(void* const* d_in, const int* in_sizes, int n_in,
                              void* d_out, int out_size, void* d_ws, size_t ws_size,
                              hipStream_t stream) {
  const float* Q = (const float*)d_in[0];
  const float* K = (const float*)d_in[1];
  const float* V = (const float*)d_in[2];
  const void* mask = d_in[3];
  const float* edge = (const float*)d_in[4];
  const float* W1 = (const float*)d_in[5];
  const float* b1 = (const float*)d_in[6];
  const float* W2 = (const float*)d_in[7];
  const float* b2 = (const float*)d_in[8];
  float* ctx = (float*)d_out;
  float* attn = ctx + QSZ;                  // outputs: context then attn
  char* ws = (char*)d_ws;
  if (ws_size < WS_NEED) return;
  _Float16* Qh = (_Float16*)(ws + OFF_QH);
  _Float16* Kh = (_Float16*)(ws + OFF_KH);
  _Float16* Vt = (_Float16*)(ws + OFF_VT);
  float* biasM = (float*)(ws + OFF_BIAS);
  int* flag = (int*)(ws + OFF_FLAG);

  (void)hipMemsetAsync(flag, 0, 4, stream);
  k_detect<<<1, 256, 0, stream>>>((const unsigned char*)mask, flag);
  k_prep_qk<<<8192, 256, 0, stream>>>(Q, K, Qh, Kh);
  k_prep_vt<<<1024, 256, 0, stream>>>(V, Vt);
  k_bias<<<8192, 256, 0, stream>>>(edge, mask, W1, b1, W2, b2, flag, biasM);
  k_attn<<<1024, 256, 0, stream>>>(Qh, Kh, Vt, biasM, ctx, attn);
}

// Round 7
// 412.471 us; speedup vs baseline: 1.2015x; 1.2015x over previous
//
#include <hip/hip_runtime.h>

// Problem constants
constexpr int NB = 8, NH = 8, NN = 1024, DK = 64, ED = 16;
constexpr long QSZ = (long)NB * NH * NN * DK;       // 4,194,304

typedef _Float16 h8 __attribute__((ext_vector_type(8)));
typedef _Float16 h4 __attribute__((ext_vector_type(4)));
typedef _Float16 h2 __attribute__((ext_vector_type(2)));
typedef float f4 __attribute__((ext_vector_type(4)));
typedef float fv16 __attribute__((ext_vector_type(16)));

// ws layout (bytes)
constexpr size_t OFF_QH = 0;                         // 8 MiB fp16 (pre-scaled by 0.125*log2e)
constexpr size_t OFF_KH = 8388608;                   // 8 MiB fp16
constexpr size_t OFF_VT = 16777216;                  // 8 MiB fp16 (transposed [bh][d][k])
constexpr size_t OFF_BIAS = 25165824;                // 16 MiB fp16 (bias*log2e, masked=-30000)
constexpr size_t OFF_FLAG = 58720256;                // 4 B
constexpr size_t WS_NEED = OFF_FLAG + 4;

constexpr float LG2E = 1.4426950408889634f;          // log2(e)
constexpr float C2 = 2.8853900817779268f;            // 2*log2(e)
constexpr float QS = 0.125f * LG2E;                  // fold 1/sqrt(dk) and log2e into Q

static __device__ __forceinline__ float fexp2(float x) {
  float r; asm("v_exp_f32 %0, %1" : "=v"(r) : "v"(x)); return r;
}
static __device__ __forceinline__ float frcp(float x) {
  float r; asm("v_rcp_f32 %0, %1" : "=v"(r) : "v"(x)); return r;
}
static __device__ __forceinline__ h2 pkrtz(float a, float b) {
  return __builtin_bit_cast(h2, __builtin_amdgcn_cvt_pkrtz(a, b));
}

// ---------- prep: Q (x 0.125*log2e) and K -> fp16, same layout ----------
__global__ __launch_bounds__(256) void k_prep_qk(
    const float* __restrict__ Q, const float* __restrict__ K,
    _Float16* __restrict__ Qh, _Float16* __restrict__ Kh) {
  int i = blockIdx.x * 256 + threadIdx.x;
  const int n4 = (int)(QSZ / 4);
  if (i < n4) {
    float4 v = reinterpret_cast<const float4*>(Q)[i];
    h4 o; o[0] = (_Float16)(v.x * QS); o[1] = (_Float16)(v.y * QS);
          o[2] = (_Float16)(v.z * QS); o[3] = (_Float16)(v.w * QS);
    reinterpret_cast<h4*>(Qh)[i] = o;
  } else {
    int j = i - n4;
    float4 v = reinterpret_cast<const float4*>(K)[j];
    h4 o; o[0] = (_Float16)v.x; o[1] = (_Float16)v.y;
          o[2] = (_Float16)v.z; o[3] = (_Float16)v.w;
    reinterpret_cast<h4*>(Kh)[j] = o;
  }
}

// ---------- prep: V [bh][k][d] fp32 -> Vt [bh][d][k] fp16 ----------
__global__ __launch_bounds__(256) void k_prep_vt(
    const float* __restrict__ V, _Float16* __restrict__ Vt) {
  int wid = (blockIdx.x * 256 + threadIdx.x) >> 6;   // 4096 waves
  int lane = threadIdx.x & 63;
  int bh = wid >> 6;
  int k0 = (wid & 63) << 4;
  const float* Vb = V + (long)bh * NN * DK;
  _Float16* Vo = Vt + (long)bh * DK * NN + (long)lane * NN + k0;
  h8 p0, p1;
#pragma unroll
  for (int i = 0; i < 16; ++i) {
    float v = Vb[(long)(k0 + i) * DK + lane];
    if (i < 8) p0[i] = (_Float16)v; else p1[i - 8] = (_Float16)v;
  }
  *reinterpret_cast<h8*>(Vo) = p0;
  *reinterpret_cast<h8*>(Vo + 8) = p1;
}

// ---------- detect mask element width (bool bytes vs int32) ----------
__global__ void k_detect(const unsigned char* __restrict__ m, int* __restrict__ flag) {
  int t = threadIdx.x;
  int any = 0;
  for (int i = t; i < 4096; i += 256)
    if ((i & 3) && m[i]) any = 1;          // int32 0/1 never has nonzero at %4!=0
  unsigned long long b = __ballot(any);
  if ((t & 63) == 0 && b) atomicOr(flag, 1);
}

// ---------- edge-bias MLP + mask fold: biasM[b][q][k] = bias*log2e fp16 ----------
// (R5 structure; output now fp16, masked = -30000)
__global__ __launch_bounds__(256) void k_bias(
    const float* __restrict__ edge, const void* __restrict__ maskp,
    const float* __restrict__ W1, const float* __restrict__ b1,
    const float* __restrict__ W2, const float* __restrict__ b2,
    const int* __restrict__ flag, _Float16* __restrict__ biasM) {
  int bq = blockIdx.x;
  int w = threadIdx.x >> 6, l = threadIdx.x & 63;
  int h = l >> 5, c31 = l & 31;
  bool isbool = (*flag != 0);
  h8 aw0, aw1;
#pragma unroll
  for (int j = 0; j < 8; ++j) {
    aw0[j] = (_Float16)(W1[(8 * h + j) * 64 + 0  + c31] * C2);
    aw1[j] = (_Float16)(W1[(8 * h + j) * 64 + 32 + c31] * C2);
  }
  fv16 cb0, cb1;
  float w20[16], w21[16];
  float sw = 0.f;
#pragma unroll
  for (int r = 0; r < 16; ++r) {
    int dr = (r & 3) + 8 * (r >> 2) + 4 * h;
    cb0[r] = b1[dr] * C2;      w20[r] = W2[dr];
    cb1[r] = b1[32 + dr] * C2; w21[r] = W2[32 + dr];
    sw += w20[r] + w21[r];
  }
  sw += __shfl_xor(sw, 32, 64);
  float base = (sw + b2[0]) * LG2E;

  const float* erow = edge + (long)bq * NN * ED;
  const float4* erow4 = reinterpret_cast<const float4*>(erow);
  _Float16* orow = biasM + (long)bq * NN;
  const int* mrowi = (const int*)maskp + (long)bq * NN;
  const unsigned char* mrowb = (const unsigned char*)maskp + (long)bq * NN;

  int kbase = w * 256;
  float4 e0a = erow4[(kbase + c31) * 4 + 2 * h];
  float4 e0b = erow4[(kbase + c31) * 4 + 2 * h + 1];
  float4 e1a = erow4[(kbase + 32 + c31) * 4 + 2 * h];
  float4 e1b = erow4[(kbase + 32 + c31) * 4 + 2 * h + 1];
#pragma unroll
  for (int p = 0; p < 4; ++p) {
    float4 n0a, n0b, n1a, n1b;
    if (p < 3) {
      int nb = kbase + 64;
      n0a = erow4[(nb + c31) * 4 + 2 * h];
      n0b = erow4[(nb + c31) * 4 + 2 * h + 1];
      n1a = erow4[(nb + 32 + c31) * 4 + 2 * h];
      n1b = erow4[(nb + 32 + c31) * 4 + 2 * h + 1];
    }
    union { h8 v; h2 q[4]; } u0, u1;
    u0.q[0] = pkrtz(e0a.x, e0a.y); u0.q[1] = pkrtz(e0a.z, e0a.w);
    u0.q[2] = pkrtz(e0b.x, e0b.y); u0.q[3] = pkrtz(e0b.z, e0b.w);
    u1.q[0] = pkrtz(e1a.x, e1a.y); u1.q[1] = pkrtz(e1a.z, e1a.w);
    u1.q[2] = pkrtz(e1b.x, e1b.y); u1.q[3] = pkrtz(e1b.z, e1b.w);
    fv16 hA0 = __builtin_amdgcn_mfma_f32_32x32x16_f16(aw0, u0.v, cb0, 0, 0, 0);
    fv16 hB0 = __builtin_amdgcn_mfma_f32_32x32x16_f16(aw1, u0.v, cb1, 0, 0, 0);
    fv16 hA1 = __builtin_amdgcn_mfma_f32_32x32x16_f16(aw0, u1.v, cb0, 0, 0, 0);
    fv16 hB1 = __builtin_amdgcn_mfma_f32_32x32x16_f16(aw1, u1.v, cb1, 0, 0, 0);
    float a00 = 0.f, a01 = 0.f, a02 = 0.f, a03 = 0.f;
    float a10 = 0.f, a11 = 0.f, a12 = 0.f, a13 = 0.f;
#pragma unroll
    for (int r = 0; r < 16; r += 4) {
      a00 = fmaf(w20[r + 0], frcp(fexp2(hA0[r + 0]) + 1.f), a00);
      a01 = fmaf(w20[r + 1], frcp(fexp2(hA0[r + 1]) + 1.f), a01);
      a02 = fmaf(w20[r + 2], frcp(fexp2(hA0[r + 2]) + 1.f), a02);
      a03 = fmaf(w20[r + 3], frcp(fexp2(hA0[r + 3]) + 1.f), a03);
      a00 = fmaf(w21[r + 0], frcp(fexp2(hB0[r + 0]) + 1.f), a00);
      a01 = fmaf(w21[r + 1], frcp(fexp2(hB0[r + 1]) + 1.f), a01);
      a02 = fmaf(w21[r + 2], frcp(fexp2(hB0[r + 2]) + 1.f), a02);
      a03 = fmaf(w21[r + 3], frcp(fexp2(hB0[r + 3]) + 1.f), a03);
      a10 = fmaf(w20[r + 0], frcp(fexp2(hA1[r + 0]) + 1.f), a10);
      a11 = fmaf(w20[r + 1], frcp(fexp2(hA1[r + 1]) + 1.f), a11);
      a12 = fmaf(w20[r + 2], frcp(fexp2(hA1[r + 2]) + 1.f), a12);
      a13 = fmaf(w20[r + 3], frcp(fexp2(hA1[r + 3]) + 1.f), a13);
      a10 = fmaf(w21[r + 0], frcp(fexp2(hB1[r + 0]) + 1.f), a10);
      a11 = fmaf(w21[r + 1], frcp(fexp2(hB1[r + 1]) + 1.f), a11);
      a12 = fmaf(w21[r + 2], frcp(fexp2(hB1[r + 2]) + 1.f), a12);
      a13 = fmaf(w21[r + 3], frcp(fexp2(hB1[r + 3]) + 1.f), a13);
    }
    float p0 = (a00 + a01) + (a02 + a03);
    float p1 = (a10 + a11) + (a12 + a13);
    p0 += __shfl_xor(p0, 32, 64);
    p1 += __shfl_xor(p1, 32, 64);
    float part = h ? p1 : p0;
    int idx = kbase + 32 * h + c31;
    int m = isbool ? (int)mrowb[idx] : mrowi[idx];
    orow[idx] = m ? (_Float16)(-30000.0f) : (_Float16)fmaf(-C2, part, base);
    e0a = n0a; e0b = n0b; e1a = n1a; e1b = n1b;
    kbase += 64;
  }
}

// ---------- fused attention (R5 structure + fp16 bias + XCD decode + prefetch) ----------
__global__ __launch_bounds__(256) void k_attn(
    const _Float16* __restrict__ Qh, const _Float16* __restrict__ Kh,
    const _Float16* __restrict__ Vt, const _Float16* __restrict__ biasH,
    float* __restrict__ ctx, float* __restrict__ attn) {
  int bid = blockIdx.x;
  // XCD-aware decode: dispatch round-robins bid%8 across XCDs, so batch
  // b = bid&7 pins each batch's 2 MiB fp16 bias slab to one XCD's L2.
  int b = bid & 7;
  int t = bid >> 3;          // 0..127
  int hh = t & 7;
  int qb = t >> 3;           // 0..15
  int bh = b * 8 + hh;
  int w = threadIdx.x >> 6, l = threadIdx.x & 63;
  int g = l >> 4, s = l & 15;
  int q0 = qb * 64 + w * 16;
  const _Float16* Qw = Qh + ((long)bh * NN + q0) * DK;
  const _Float16* Kb = Kh + (long)bh * NN * DK;
  const _Float16* Vb = Vt + (long)bh * DK * NN;
  const _Float16* bias0 = biasH + (long)b * NN * NN + (long)q0 * NN;
  const _Float16* br0 = bias0 + (long)(4 * g + 0) * NN + s;
  const _Float16* br1 = bias0 + (long)(4 * g + 1) * NN + s;
  const _Float16* br2 = bias0 + (long)(4 * g + 2) * NN + s;
  const _Float16* br3 = bias0 + (long)(4 * g + 3) * NN + s;
  h8 aQ0 = *reinterpret_cast<const h8*>(Qw + s * DK + 8 * g);
  h8 aQ1 = *reinterpret_cast<const h8*>(Qw + s * DK + 32 + 8 * g);

  // ---- pass 1: row sums of exp2(S'), depth-1 prefetch of K + bias ----
  float ls0 = 0.f, ls1 = 0.f, ls2 = 0.f, ls3 = 0.f;
  h8 ka0, ka1, kb0, kb1, na0, na1, nb0, nb1;
  _Float16 bc[8], bn[8];
  {
    const _Float16* kp = Kb + (long)s * DK + 8 * g;
    ka0 = *reinterpret_cast<const h8*>(kp);
    ka1 = *reinterpret_cast<const h8*>(kp + 32);
    const _Float16* kq = Kb + (long)(16 + s) * DK + 8 * g;
    kb0 = *reinterpret_cast<const h8*>(kq);
    kb1 = *reinterpret_cast<const h8*>(kq + 32);
    bc[0] = br0[0];  bc[1] = br1[0];  bc[2] = br2[0];  bc[3] = br3[0];
    bc[4] = br0[16]; bc[5] = br1[16]; bc[6] = br2[16]; bc[7] = br3[16];
  }
  for (int c0 = 0; c0 < NN; c0 += 32) {
    int cn = (c0 + 32) & (NN - 1);       // wrapped: branchless, always valid
    const _Float16* kp = Kb + (long)(cn + s) * DK + 8 * g;
    na0 = *reinterpret_cast<const h8*>(kp);
    na1 = *reinterpret_cast<const h8*>(kp + 32);
    const _Float16* kq = Kb + (long)(cn + 16 + s) * DK + 8 * g;
    nb0 = *reinterpret_cast<const h8*>(kq);
    nb1 = *reinterpret_cast<const h8*>(kq + 32);
    bn[0] = br0[cn];      bn[1] = br1[cn];      bn[2] = br2[cn];      bn[3] = br3[cn];
    bn[4] = br0[cn + 16]; bn[5] = br1[cn + 16]; bn[6] = br2[cn + 16]; bn[7] = br3[cn + 16];
    f4 z = {0.f, 0.f, 0.f, 0.f};
    f4 acc = __builtin_amdgcn_mfma_f32_16x16x32_f16(aQ0, ka0, z, 0, 0, 0);
    acc = __builtin_amdgcn_mfma_f32_16x16x32_f16(aQ1, ka1, acc, 0, 0, 0);
    ls0 += fexp2(acc[0] + (float)bc[0]);
    ls1 += fexp2(acc[1] + (float)bc[1]);
    ls2 += fexp2(acc[2] + (float)bc[2]);
    ls3 += fexp2(acc[3] + (float)bc[3]);
    acc = __builtin_amdgcn_mfma_f32_16x16x32_f16(aQ0, kb0, z, 0, 0, 0);
    acc = __builtin_amdgcn_mfma_f32_16x16x32_f16(aQ1, kb1, acc, 0, 0, 0);
    ls0 += fexp2(acc[0] + (float)bc[4]);
    ls1 += fexp2(acc[1] + (float)bc[5]);
    ls2 += fexp2(acc[2] + (float)bc[6]);
    ls3 += fexp2(acc[3] + (float)bc[7]);
    ka0 = na0; ka1 = na1; kb0 = nb0; kb1 = nb1;
#pragma unroll
    for (int i = 0; i < 8; ++i) bc[i] = bn[i];
  }
#pragma unroll
  for (int m = 1; m < 16; m <<= 1) {
    ls0 += __shfl_xor(ls0, m, 64);
    ls1 += __shfl_xor(ls1, m, 64);
    ls2 += __shfl_xor(ls2, m, 64);
    ls3 += __shfl_xor(ls3, m, 64);
  }
  float iv0 = frcp(ls0), iv1 = frcp(ls1), iv2 = frcp(ls2), iv3 = frcp(ls3);

  // ---- pass 2: recompute S', write attn, accumulate PV (LDS P, K=32) ----
  __shared__ _Float16 plds[4][16][40];   // per-wave P chunk [16 q][32 kv], pitch 40
  f4 ca0 = {0.f,0.f,0.f,0.f}, ca1 = {0.f,0.f,0.f,0.f};
  f4 ca2 = {0.f,0.f,0.f,0.f}, ca3 = {0.f,0.f,0.f,0.f};
  float* attnw = attn + ((long)bh * NN + q0) * NN;
  {
    const _Float16* kp = Kb + (long)s * DK + 8 * g;
    ka0 = *reinterpret_cast<const h8*>(kp);
    ka1 = *reinterpret_cast<const h8*>(kp + 32);
    const _Float16* kq = Kb + (long)(16 + s) * DK + 8 * g;
    kb0 = *reinterpret_cast<const h8*>(kq);
    kb1 = *reinterpret_cast<const h8*>(kq + 32);
    bc[0] = br0[0];  bc[1] = br1[0];  bc[2] = br2[0];  bc[3] = br3[0];
    bc[4] = br0[16]; bc[5] = br1[16]; bc[6] = br2[16]; bc[7] = br3[16];
  }
  for (int c0 = 0; c0 < NN; c0 += 32) {
    int cn = (c0 + 32) & (NN - 1);
    const _Float16* kp = Kb + (long)(cn + s) * DK + 8 * g;
    na0 = *reinterpret_cast<const h8*>(kp);
    na1 = *reinterpret_cast<const h8*>(kp + 32);
    const _Float16* kq = Kb + (long)(cn + 16 + s) * DK + 8 * g;
    nb0 = *reinterpret_cast<const h8*>(kq);
    nb1 = *reinterpret_cast<const h8*>(kq + 32);
    bn[0] = br0[cn];      bn[1] = br1[cn];      bn[2] = br2[cn];      bn[3] = br3[cn];
    bn[4] = br0[cn + 16]; bn[5] = br1[cn + 16]; bn[6] = br2[cn + 16]; bn[7] = br3[cn + 16];
    // V-frags for this chunk (independent of serial chain; compiler hoists)
    const _Float16* vp = Vb + (long)s * NN + c0 + 8 * g;
    h8 bv0 = *reinterpret_cast<const h8*>(vp);
    h8 bv1 = *reinterpret_cast<const h8*>(vp + 16 * NN);
    h8 bv2 = *reinterpret_cast<const h8*>(vp + 32 * NN);
    h8 bv3 = *reinterpret_cast<const h8*>(vp + 48 * NN);
    f4 z = {0.f, 0.f, 0.f, 0.f};
    // ct = 0
    f4 acc = __builtin_amdgcn_mfma_f32_16x16x32_f16(aQ0, ka0, z, 0, 0, 0);
    acc = __builtin_amdgcn_mfma_f32_16x16x32_f16(aQ1, ka1, acc, 0, 0, 0);
    {
      float p0 = fexp2(acc[0] + (float)bc[0]) * iv0;
      float p1 = fexp2(acc[1] + (float)bc[1]) * iv1;
      float p2 = fexp2(acc[2] + (float)bc[2]) * iv2;
      float p3 = fexp2(acc[3] + (float)bc[3]) * iv3;
      attnw[(4 * g + 0) * NN + c0 + s] = p0;
      attnw[(4 * g + 1) * NN + c0 + s] = p1;
      attnw[(4 * g + 2) * NN + c0 + s] = p2;
      attnw[(4 * g + 3) * NN + c0 + s] = p3;
      plds[w][4 * g + 0][s] = (_Float16)p0;
      plds[w][4 * g + 1][s] = (_Float16)p1;
      plds[w][4 * g + 2][s] = (_Float16)p2;
      plds[w][4 * g + 3][s] = (_Float16)p3;
    }
    // ct = 1
    acc = __builtin_amdgcn_mfma_f32_16x16x32_f16(aQ0, kb0, z, 0, 0, 0);
    acc = __builtin_amdgcn_mfma_f32_16x16x32_f16(aQ1, kb1, acc, 0, 0, 0);
    {
      float p0 = fexp2(acc[0] + (float)bc[4]) * iv0;
      float p1 = fexp2(acc[1] + (float)bc[5]) * iv1;
      float p2 = fexp2(acc[2] + (float)bc[6]) * iv2;
      float p3 = fexp2(acc[3] + (float)bc[7]) * iv3;
      attnw[(4 * g + 0) * NN + c0 + 16 + s] = p0;
      attnw[(4 * g + 1) * NN + c0 + 16 + s] = p1;
      attnw[(4 * g + 2) * NN + c0 + 16 + s] = p2;
      attnw[(4 * g + 3) * NN + c0 + 16 + s] = p3;
      plds[w][4 * g + 0][16 + s] = (_Float16)p0;
      plds[w][4 * g + 1][16 + s] = (_Float16)p1;
      plds[w][4 * g + 2][16 + s] = (_Float16)p2;
      plds[w][4 * g + 3][16 + s] = (_Float16)p3;
    }
    h8 aP = *reinterpret_cast<const h8*>(&plds[w][s][8 * g]);
    ca0 = __builtin_amdgcn_mfma_f32_16x16x32_f16(aP, bv0, ca0, 0, 0, 0);
    ca1 = __builtin_amdgcn_mfma_f32_16x16x32_f16(aP, bv1, ca1, 0, 0, 0);
    ca2 = __builtin_amdgcn_mfma_f32_16x16x32_f16(aP, bv2, ca2, 0, 0, 0);
    ca3 = __builtin_amdgcn_mfma_f32_16x16x32_f16(aP, bv3, ca3, 0, 0, 0);
    ka0 = na0; ka1 = na1; kb0 = nb0; kb1 = nb1;
#pragma unroll
    for (int i = 0; i < 8; ++i) bc[i] = bn[i];
  }
  float* cw = ctx + ((long)bh * NN + q0) * DK;
#pragma unroll
  for (int j = 0; j < 4; ++j) {
    cw[(4 * g + j) * DK + 0  + s] = ca0[j];
    cw[(4 * g + j) * DK + 16 + s] = ca1[j];
    cw[(4 * g + j) * DK + 32 + s] = ca2[j];
    cw[(4 * g + j) * DK + 48 + s] = ca3[j];
  }
}

extern "C" void kernel_launch(void* const* d_in, const int* in_sizes, int n_in,
                              void* d_out, int out_size, void* d_ws, size_t ws_size,
                              hipStream_t stream) {
  const float* Q = (const float*)d_in[0];
  const float* K = (const float*)d_in[1];
  const float* V = (const float*)d_in[2];
  const void* mask = d_in[3];
  const float* edge = (const float*)d_in[4];
  const float* W1 = (const float*)d_in[5];
  const float* b1 = (const float*)d_in[6];
  const float* W2 = (const float*)d_in[7];
  const float* b2 = (const float*)d_in[8];
  float* ctx = (float*)d_out;
  float* attn = ctx + QSZ;                  // outputs: context then attn
  char* ws = (char*)d_ws;
  if (ws_size < WS_NEED) return;
  _Float16* Qh = (_Float16*)(ws + OFF_QH);
  _Float16* Kh = (_Float16*)(ws + OFF_KH);
  _Float16* Vt = (_Float16*)(ws + OFF_VT);
  _Float16* biasM = (_Float16*)(ws + OFF_BIAS);
  int* flag = (int*)(ws + OFF_FLAG);

  (void)hipMemsetAsync(flag, 0, 4, stream);
  k_detect<<<1, 256, 0, stream>>>((const unsigned char*)mask, flag);
  k_prep_qk<<<8192, 256, 0, stream>>>(Q, K, Qh, Kh);
  k_prep_vt<<<1024, 256, 0, stream>>>(V, Vt);
  k_bias<<<8192, 256, 0, stream>>>(edge, mask, W1, b1, W2, b2, flag, biasM);
  k_attn<<<1024, 256, 0, stream>>>(Qh, Kh, Vt, biasM, ctx, attn);
}

// Round 8
// 392.421 us; speedup vs baseline: 1.2629x; 1.0511x over previous
//
#include <hip/hip_runtime.h>

// Problem constants
constexpr int NB = 8, NH = 8, NN = 1024, DK = 64, ED = 16;
constexpr long QSZ = (long)NB * NH * NN * DK;       // 4,194,304

typedef _Float16 h8 __attribute__((ext_vector_type(8)));
typedef _Float16 h4 __attribute__((ext_vector_type(4)));
typedef _Float16 h2 __attribute__((ext_vector_type(2)));
typedef float f4 __attribute__((ext_vector_type(4)));
typedef float fv16 __attribute__((ext_vector_type(16)));

// ws layout (bytes)
constexpr size_t OFF_QH = 0;                         // 8 MiB fp16 (pre-scaled by 0.125*log2e)
constexpr size_t OFF_KH = 8388608;                   // 8 MiB fp16
constexpr size_t OFF_VT = 16777216;                  // 8 MiB fp16 (transposed [bh][d][k])
constexpr size_t OFF_BIAS = 25165824;                // 16 MiB fp16 (bias*log2e, masked=-30000)
constexpr size_t OFF_FLAG = 58720256;                // 4 B
constexpr size_t WS_NEED = OFF_FLAG + 4;

constexpr float LG2E = 1.4426950408889634f;          // log2(e)
constexpr float C2 = 2.8853900817779268f;            // 2*log2(e)
constexpr float QS = 0.125f * LG2E;                  // fold 1/sqrt(dk) and log2e into Q

static __device__ __forceinline__ float fexp2(float x) {
  float r; asm("v_exp_f32 %0, %1" : "=v"(r) : "v"(x)); return r;
}
static __device__ __forceinline__ float frcp(float x) {
  float r; asm("v_rcp_f32 %0, %1" : "=v"(r) : "v"(x)); return r;
}
static __device__ __forceinline__ h2 pkrtz(float a, float b) {
  return __builtin_bit_cast(h2, __builtin_amdgcn_cvt_pkrtz(a, b));
}

// ---------- prep: Q (x 0.125*log2e) and K -> fp16, same layout ----------
__global__ __launch_bounds__(256) void k_prep_qk(
    const float* __restrict__ Q, const float* __restrict__ K,
    _Float16* __restrict__ Qh, _Float16* __restrict__ Kh) {
  int i = blockIdx.x * 256 + threadIdx.x;
  const int n4 = (int)(QSZ / 4);
  if (i < n4) {
    float4 v = reinterpret_cast<const float4*>(Q)[i];
    h4 o; o[0] = (_Float16)(v.x * QS); o[1] = (_Float16)(v.y * QS);
          o[2] = (_Float16)(v.z * QS); o[3] = (_Float16)(v.w * QS);
    reinterpret_cast<h4*>(Qh)[i] = o;
  } else {
    int j = i - n4;
    float4 v = reinterpret_cast<const float4*>(K)[j];
    h4 o; o[0] = (_Float16)v.x; o[1] = (_Float16)v.y;
          o[2] = (_Float16)v.z; o[3] = (_Float16)v.w;
    reinterpret_cast<h4*>(Kh)[j] = o;
  }
}

// ---------- prep: V [bh][k][d] fp32 -> Vt [bh][d][k] fp16 ----------
__global__ __launch_bounds__(256) void k_prep_vt(
    const float* __restrict__ V, _Float16* __restrict__ Vt) {
  int wid = (blockIdx.x * 256 + threadIdx.x) >> 6;   // 4096 waves
  int lane = threadIdx.x & 63;
  int bh = wid >> 6;
  int k0 = (wid & 63) << 4;
  const float* Vb = V + (long)bh * NN * DK;
  _Float16* Vo = Vt + (long)bh * DK * NN + (long)lane * NN + k0;
  h8 p0, p1;
#pragma unroll
  for (int i = 0; i < 16; ++i) {
    float v = Vb[(long)(k0 + i) * DK + lane];
    if (i < 8) p0[i] = (_Float16)v; else p1[i - 8] = (_Float16)v;
  }
  *reinterpret_cast<h8*>(Vo) = p0;
  *reinterpret_cast<h8*>(Vo + 8) = p1;
}

// ---------- detect mask element width (bool bytes vs int32) ----------
__global__ void k_detect(const unsigned char* __restrict__ m, int* __restrict__ flag) {
  int t = threadIdx.x;
  int any = 0;
  for (int i = t; i < 4096; i += 256)
    if ((i & 3) && m[i]) any = 1;          // int32 0/1 never has nonzero at %4!=0
  unsigned long long b = __ballot(any);
  if ((t & 63) == 0 && b) atomicOr(flag, 1);
}

// ---------- edge-bias MLP + mask fold: biasM[b][q][k] = bias*log2e fp16 ----------
// Register-diet version: packed h2 tables for (b1*C2, W2), C=0 MFMA, paired
// h-matrix processing (peak live h = 32 regs), __launch_bounds__(256,3) to
// guarantee >=3 waves/SIMD so load/trans/VALU phases overlap across waves.
__global__ __launch_bounds__(256, 3) void k_bias(
    const float* __restrict__ edge, const void* __restrict__ maskp,
    const float* __restrict__ W1, const float* __restrict__ b1,
    const float* __restrict__ W2, const float* __restrict__ b2,
    const int* __restrict__ flag, _Float16* __restrict__ biasM) {
  int bq = blockIdx.x;
  int w = threadIdx.x >> 6, l = threadIdx.x & 63;
  int h = l >> 5, c31 = l & 31;
  bool isbool = (*flag != 0);
  h8 aw0, aw1;
#pragma unroll
  for (int j = 0; j < 8; ++j) {
    aw0[j] = (_Float16)(W1[(8 * h + j) * 64 + 0  + c31] * C2);
    aw1[j] = (_Float16)(W1[(8 * h + j) * 64 + 32 + c31] * C2);
  }
  // packed tables: pb[r] = (b1C2[dr], b1C2[32+dr]); pw[r] = (W2[dr], W2[32+dr])
  h2 pb[16], pw[16];
  float sw = 0.f;
#pragma unroll
  for (int r = 0; r < 16; ++r) {
    int dr = (r & 3) + 8 * (r >> 2) + 4 * h;
    float b0 = b1[dr] * C2, b1v = b1[32 + dr] * C2;
    float w0 = W2[dr], w1v = W2[32 + dr];
    pb[r] = pkrtz(b0, b1v);
    pw[r] = pkrtz(w0, w1v);
    sw += w0 + w1v;
  }
  sw += __shfl_xor(sw, 32, 64);
  float base = (sw + b2[0]) * LG2E;

  const float* erow = edge + (long)bq * NN * ED;
  const float4* erow4 = reinterpret_cast<const float4*>(erow);
  _Float16* orow = biasM + (long)bq * NN;
  const int* mrowi = (const int*)maskp + (long)bq * NN;
  const unsigned char* mrowb = (const unsigned char*)maskp + (long)bq * NN;

  fv16 z;
#pragma unroll
  for (int r = 0; r < 16; ++r) z[r] = 0.f;

  int kbase = w * 256;
  float4 e0a = erow4[(kbase + c31) * 4 + 2 * h];
  float4 e0b = erow4[(kbase + c31) * 4 + 2 * h + 1];
  float4 e1a = erow4[(kbase + 32 + c31) * 4 + 2 * h];
  float4 e1b = erow4[(kbase + 32 + c31) * 4 + 2 * h + 1];
#pragma unroll
  for (int p = 0; p < 4; ++p) {
    float4 n0a, n0b, n1a, n1b;
    if (p < 3) {
      int nb = kbase + 64;
      n0a = erow4[(nb + c31) * 4 + 2 * h];
      n0b = erow4[(nb + c31) * 4 + 2 * h + 1];
      n1a = erow4[(nb + 32 + c31) * 4 + 2 * h];
      n1b = erow4[(nb + 32 + c31) * 4 + 2 * h + 1];
    }
    union { h8 v; h2 q[4]; } u0, u1;
    u0.q[0] = pkrtz(e0a.x, e0a.y); u0.q[1] = pkrtz(e0a.z, e0a.w);
    u0.q[2] = pkrtz(e0b.x, e0b.y); u0.q[3] = pkrtz(e0b.z, e0b.w);
    u1.q[0] = pkrtz(e1a.x, e1a.y); u1.q[1] = pkrtz(e1a.z, e1a.w);
    u1.q[2] = pkrtz(e1b.x, e1b.y); u1.q[3] = pkrtz(e1b.z, e1b.w);
    float a00 = 0.f, a01 = 0.f, a10 = 0.f, a11 = 0.f;
    // --- d-lo half (aw0), both kv-chunks ---
    {
      fv16 hA0 = __builtin_amdgcn_mfma_f32_32x32x16_f16(aw0, u0.v, z, 0, 0, 0);
      fv16 hA1 = __builtin_amdgcn_mfma_f32_32x32x16_f16(aw0, u1.v, z, 0, 0, 0);
#pragma unroll
      for (int r = 0; r < 16; ++r) {
        float bb = (float)pb[r][0];
        float ww = (float)pw[r][0];
        if (r & 1) {
          a01 = fmaf(ww, frcp(fexp2(hA0[r] + bb) + 1.f), a01);
          a11 = fmaf(ww, frcp(fexp2(hA1[r] + bb) + 1.f), a11);
        } else {
          a00 = fmaf(ww, frcp(fexp2(hA0[r] + bb) + 1.f), a00);
          a10 = fmaf(ww, frcp(fexp2(hA1[r] + bb) + 1.f), a10);
        }
      }
    }
    // --- d-hi half (aw1), both kv-chunks ---
    {
      fv16 hB0 = __builtin_amdgcn_mfma_f32_32x32x16_f16(aw1, u0.v, z, 0, 0, 0);
      fv16 hB1 = __builtin_amdgcn_mfma_f32_32x32x16_f16(aw1, u1.v, z, 0, 0, 0);
#pragma unroll
      for (int r = 0; r < 16; ++r) {
        float bb = (float)pb[r][1];
        float ww = (float)pw[r][1];
        if (r & 1) {
          a01 = fmaf(ww, frcp(fexp2(hB0[r] + bb) + 1.f), a01);
          a11 = fmaf(ww, frcp(fexp2(hB1[r] + bb) + 1.f), a11);
        } else {
          a00 = fmaf(ww, frcp(fexp2(hB0[r] + bb) + 1.f), a00);
          a10 = fmaf(ww, frcp(fexp2(hB1[r] + bb) + 1.f), a10);
        }
      }
    }
    float p0 = a00 + a01;
    float p1 = a10 + a11;
    p0 += __shfl_xor(p0, 32, 64);
    p1 += __shfl_xor(p1, 32, 64);
    float part = h ? p1 : p0;
    int idx = kbase + 32 * h + c31;
    int m = isbool ? (int)mrowb[idx] : mrowi[idx];
    orow[idx] = m ? (_Float16)(-30000.0f) : (_Float16)fmaf(-C2, part, base);
    e0a = n0a; e0b = n0b; e1a = n1a; e1b = n1b;
    kbase += 64;
  }
}

// ---------- fused attention (unchanged from R7) ----------
__global__ __launch_bounds__(256) void k_attn(
    const _Float16* __restrict__ Qh, const _Float16* __restrict__ Kh,
    const _Float16* __restrict__ Vt, const _Float16* __restrict__ biasH,
    float* __restrict__ ctx, float* __restrict__ attn) {
  int bid = blockIdx.x;
  int b = bid & 7;
  int t = bid >> 3;          // 0..127
  int hh = t & 7;
  int qb = t >> 3;           // 0..15
  int bh = b * 8 + hh;
  int w = threadIdx.x >> 6, l = threadIdx.x & 63;
  int g = l >> 4, s = l & 15;
  int q0 = qb * 64 + w * 16;
  const _Float16* Qw = Qh + ((long)bh * NN + q0) * DK;
  const _Float16* Kb = Kh + (long)bh * NN * DK;
  const _Float16* Vb = Vt + (long)bh * DK * NN;
  const _Float16* bias0 = biasH + (long)b * NN * NN + (long)q0 * NN;
  const _Float16* br0 = bias0 + (long)(4 * g + 0) * NN + s;
  const _Float16* br1 = bias0 + (long)(4 * g + 1) * NN + s;
  const _Float16* br2 = bias0 + (long)(4 * g + 2) * NN + s;
  const _Float16* br3 = bias0 + (long)(4 * g + 3) * NN + s;
  h8 aQ0 = *reinterpret_cast<const h8*>(Qw + s * DK + 8 * g);
  h8 aQ1 = *reinterpret_cast<const h8*>(Qw + s * DK + 32 + 8 * g);

  // ---- pass 1: row sums of exp2(S'), depth-1 prefetch of K + bias ----
  float ls0 = 0.f, ls1 = 0.f, ls2 = 0.f, ls3 = 0.f;
  h8 ka0, ka1, kb0, kb1, na0, na1, nb0, nb1;
  _Float16 bc[8], bn[8];
  {
    const _Float16* kp = Kb + (long)s * DK + 8 * g;
    ka0 = *reinterpret_cast<const h8*>(kp);
    ka1 = *reinterpret_cast<const h8*>(kp + 32);
    const _Float16* kq = Kb + (long)(16 + s) * DK + 8 * g;
    kb0 = *reinterpret_cast<const h8*>(kq);
    kb1 = *reinterpret_cast<const h8*>(kq + 32);
    bc[0] = br0[0];  bc[1] = br1[0];  bc[2] = br2[0];  bc[3] = br3[0];
    bc[4] = br0[16]; bc[5] = br1[16]; bc[6] = br2[16]; bc[7] = br3[16];
  }
  for (int c0 = 0; c0 < NN; c0 += 32) {
    int cn = (c0 + 32) & (NN - 1);       // wrapped: branchless, always valid
    const _Float16* kp = Kb + (long)(cn + s) * DK + 8 * g;
    na0 = *reinterpret_cast<const h8*>(kp);
    na1 = *reinterpret_cast<const h8*>(kp + 32);
    const _Float16* kq = Kb + (long)(cn + 16 + s) * DK + 8 * g;
    nb0 = *reinterpret_cast<const h8*>(kq);
    nb1 = *reinterpret_cast<const h8*>(kq + 32);
    bn[0] = br0[cn];      bn[1] = br1[cn];      bn[2] = br2[cn];      bn[3] = br3[cn];
    bn[4] = br0[cn + 16]; bn[5] = br1[cn + 16]; bn[6] = br2[cn + 16]; bn[7] = br3[cn + 16];
    f4 z = {0.f, 0.f, 0.f, 0.f};
    f4 acc = __builtin_amdgcn_mfma_f32_16x16x32_f16(aQ0, ka0, z, 0, 0, 0);
    acc = __builtin_amdgcn_mfma_f32_16x16x32_f16(aQ1, ka1, acc, 0, 0, 0);
    ls0 += fexp2(acc[0] + (float)bc[0]);
    ls1 += fexp2(acc[1] + (float)bc[1]);
    ls2 += fexp2(acc[2] + (float)bc[2]);
    ls3 += fexp2(acc[3] + (float)bc[3]);
    acc = __builtin_amdgcn_mfma_f32_16x16x32_f16(aQ0, kb0, z, 0, 0, 0);
    acc = __builtin_amdgcn_mfma_f32_16x16x32_f16(aQ1, kb1, acc, 0, 0, 0);
    ls0 += fexp2(acc[0] + (float)bc[4]);
    ls1 += fexp2(acc[1] + (float)bc[5]);
    ls2 += fexp2(acc[2] + (float)bc[6]);
    ls3 += fexp2(acc[3] + (float)bc[7]);
    ka0 = na0; ka1 = na1; kb0 = nb0; kb1 = nb1;
#pragma unroll
    for (int i = 0; i < 8; ++i) bc[i] = bn[i];
  }
#pragma unroll
  for (int m = 1; m < 16; m <<= 1) {
    ls0 += __shfl_xor(ls0, m, 64);
    ls1 += __shfl_xor(ls1, m, 64);
    ls2 += __shfl_xor(ls2, m, 64);
    ls3 += __shfl_xor(ls3, m, 64);
  }
  float iv0 = frcp(ls0), iv1 = frcp(ls1), iv2 = frcp(ls2), iv3 = frcp(ls3);

  // ---- pass 2: recompute S', write attn, accumulate PV (LDS P, K=32) ----
  __shared__ _Float16 plds[4][16][40];   // per-wave P chunk [16 q][32 kv], pitch 40
  f4 ca0 = {0.f,0.f,0.f,0.f}, ca1 = {0.f,0.f,0.f,0.f};
  f4 ca2 = {0.f,0.f,0.f,0.f}, ca3 = {0.f,0.f,0.f,0.f};
  float* attnw = attn + ((long)bh * NN + q0) * NN;
  {
    const _Float16* kp = Kb + (long)s * DK + 8 * g;
    ka0 = *reinterpret_cast<const h8*>(kp);
    ka1 = *reinterpret_cast<const h8*>(kp + 32);
    const _Float16* kq = Kb + (long)(16 + s) * DK + 8 * g;
    kb0 = *reinterpret_cast<const h8*>(kq);
    kb1 = *reinterpret_cast<const h8*>(kq + 32);
    bc[0] = br0[0];  bc[1] = br1[0];  bc[2] = br2[0];  bc[3] = br3[0];
    bc[4] = br0[16]; bc[5] = br1[16]; bc[6] = br2[16]; bc[7] = br3[16];
  }
  for (int c0 = 0; c0 < NN; c0 += 32) {
    int cn = (c0 + 32) & (NN - 1);
    const _Float16* kp = Kb + (long)(cn + s) * DK + 8 * g;
    na0 = *reinterpret_cast<const h8*>(kp);
    na1 = *reinterpret_cast<const h8*>(kp + 32);
    const _Float16* kq = Kb + (long)(cn + 16 + s) * DK + 8 * g;
    nb0 = *reinterpret_cast<const h8*>(kq);
    nb1 = *reinterpret_cast<const h8*>(kq + 32);
    bn[0] = br0[cn];      bn[1] = br1[cn];      bn[2] = br2[cn];      bn[3] = br3[cn];
    bn[4] = br0[cn + 16]; bn[5] = br1[cn + 16]; bn[6] = br2[cn + 16]; bn[7] = br3[cn + 16];
    const _Float16* vp = Vb + (long)s * NN + c0 + 8 * g;
    h8 bv0 = *reinterpret_cast<const h8*>(vp);
    h8 bv1 = *reinterpret_cast<const h8*>(vp + 16 * NN);
    h8 bv2 = *reinterpret_cast<const h8*>(vp + 32 * NN);
    h8 bv3 = *reinterpret_cast<const h8*>(vp + 48 * NN);
    f4 z = {0.f, 0.f, 0.f, 0.f};
    // ct = 0
    f4 acc = __builtin_amdgcn_mfma_f32_16x16x32_f16(aQ0, ka0, z, 0, 0, 0);
    acc = __builtin_amdgcn_mfma_f32_16x16x32_f16(aQ1, ka1, acc, 0, 0, 0);
    {
      float p0 = fexp2(acc[0] + (float)bc[0]) * iv0;
      float p1 = fexp2(acc[1] + (float)bc[1]) * iv1;
      float p2 = fexp2(acc[2] + (float)bc[2]) * iv2;
      float p3 = fexp2(acc[3] + (float)bc[3]) * iv3;
      attnw[(4 * g + 0) * NN + c0 + s] = p0;
      attnw[(4 * g + 1) * NN + c0 + s] = p1;
      attnw[(4 * g + 2) * NN + c0 + s] = p2;
      attnw[(4 * g + 3) * NN + c0 + s] = p3;
      plds[w][4 * g + 0][s] = (_Float16)p0;
      plds[w][4 * g + 1][s] = (_Float16)p1;
      plds[w][4 * g + 2][s] = (_Float16)p2;
      plds[w][4 * g + 3][s] = (_Float16)p3;
    }
    // ct = 1
    acc = __builtin_amdgcn_mfma_f32_16x16x32_f16(aQ0, kb0, z, 0, 0, 0);
    acc = __builtin_amdgcn_mfma_f32_16x16x32_f16(aQ1, kb1, acc, 0, 0, 0);
    {
      float p0 = fexp2(acc[0] + (float)bc[4]) * iv0;
      float p1 = fexp2(acc[1] + (float)bc[5]) * iv1;
      float p2 = fexp2(acc[2] + (float)bc[6]) * iv2;
      float p3 = fexp2(acc[3] + (float)bc[7]) * iv3;
      attnw[(4 * g + 0) * NN + c0 + 16 + s] = p0;
      attnw[(4 * g + 1) * NN + c0 + 16 + s] = p1;
      attnw[(4 * g + 2) * NN + c0 + 16 + s] = p2;
      attnw[(4 * g + 3) * NN + c0 + 16 + s] = p3;
      plds[w][4 * g + 0][16 + s] = (_Float16)p0;
      plds[w][4 * g + 1][16 + s] = (_Float16)p1;
      plds[w][4 * g + 2][16 + s] = (_Float16)p2;
      plds[w][4 * g + 3][16 + s] = (_Float16)p3;
    }
    h8 aP = *reinterpret_cast<const h8*>(&plds[w][s][8 * g]);
    ca0 = __builtin_amdgcn_mfma_f32_16x16x32_f16(aP, bv0, ca0, 0, 0, 0);
    ca1 = __builtin_amdgcn_mfma_f32_16x16x32_f16(aP, bv1, ca1, 0, 0, 0);
    ca2 = __builtin_amdgcn_mfma_f32_16x16x32_f16(aP, bv2, ca2, 0, 0, 0);
    ca3 = __builtin_amdgcn_mfma_f32_16x16x32_f16(aP, bv3, ca3, 0, 0, 0);
    ka0 = na0; ka1 = na1; kb0 = nb0; kb1 = nb1;
#pragma unroll
    for (int i = 0; i < 8; ++i) bc[i] = bn[i];
  }
  float* cw = ctx + ((long)bh * NN + q0) * DK;
#pragma unroll
  for (int j = 0; j < 4; ++j) {
    cw[(4 * g + j) * DK + 0  + s] = ca0[j];
    cw[(4 * g + j) * DK + 16 + s] = ca1[j];
    cw[(4 * g + j) * DK + 32 + s] = ca2[j];
    cw[(4 * g + j) * DK + 48 + s] = ca3[j];
  }
}

extern "C" void kernel_launch(void* const* d_in, const int* in_sizes, int n_in,
                              void* d_out, int out_size, void* d_ws, size_t ws_size,
                              hipStream_t stream) {
  const float* Q = (const float*)d_in[0];
  const float* K = (const float*)d_in[1];
  const float* V = (const float*)d_in[2];
  const void* mask = d_in[3];
  const float* edge = (const float*)d_in[4];
  const float* W1 = (const float*)d_in[5];
  const float* b1 = (const float*)d_in[6];
  const float* W2 = (const float*)d_in[7];
  const float* b2 = (const float*)d_in[8];
  float* ctx = (float*)d_out;
  float* attn = ctx + QSZ;                  // outputs: context then attn
  char* ws = (char*)d_ws;
  if (ws_size < WS_NEED) return;
  _Float16* Qh = (_Float16*)(ws + OFF_QH);
  _Float16* Kh = (_Float16*)(ws + OFF_KH);
  _Float16* Vt = (_Float16*)(ws + OFF_VT);
  _Float16* biasM = (_Float16*)(ws + OFF_BIAS);
  int* flag = (int*)(ws + OFF_FLAG);

  (void)hipMemsetAsync(flag, 0, 4, stream);
  k_detect<<<1, 256, 0, stream>>>((const unsigned char*)mask, flag);
  k_prep_qk<<<8192, 256, 0, stream>>>(Q, K, Qh, Kh);
  k_prep_vt<<<1024, 256, 0, stream>>>(V, Vt);
  k_bias<<<8192, 256, 0, stream>>>(edge, mask, W1, b1, W2, b2, flag, biasM);
  k_attn<<<1024, 256, 0, stream>>>(Qh, Kh, Vt, biasM, ctx, attn);
}